// Round 2
// baseline (143.127 us; speedup 1.0000x reference)
//
#include <hip/hip_runtime.h>
#include <hip/hip_bf16.h>
#include <math.h>

#define BB 16
#define CC 3
#define HH 336
#define WW 1078
#define HW (HH * WW)

// ---------------------------------------------------------------------------
// Kernel 1: per-batch DLT homography solve (8x8, partial-pivot GE in double).
// Matches reference A layout:
//   row 2i  : [x, y, 1, 0, 0, 0, -u*x, -u*y]  = u
//   row 2i+1: [0, 0, 0, x, y, 1, -v*x, -v*y]  = v
// Result: H (9 floats, H[8]=1) per batch into Hout.
// ---------------------------------------------------------------------------
__global__ void homography_kernel(const float* __restrict__ src_pt,
                                  const float* __restrict__ dst_pt,
                                  float* __restrict__ Hout) {
    int b = threadIdx.x;
    if (b >= BB) return;

    double A[8][9];
    const float* sp = src_pt + b * 8;
    const float* dp = dst_pt + b * 8;
    for (int i = 0; i < 4; ++i) {
        double x = (double)sp[2 * i], y = (double)sp[2 * i + 1];
        double u = (double)dp[2 * i], v = (double)dp[2 * i + 1];
        double* r0 = A[2 * i];
        double* r1 = A[2 * i + 1];
        r0[0] = x;  r0[1] = y;  r0[2] = 1.0; r0[3] = 0.0; r0[4] = 0.0; r0[5] = 0.0;
        r0[6] = -u * x; r0[7] = -u * y; r0[8] = u;
        r1[0] = 0.0; r1[1] = 0.0; r1[2] = 0.0; r1[3] = x;  r1[4] = y;  r1[5] = 1.0;
        r1[6] = -v * x; r1[7] = -v * y; r1[8] = v;
    }

    // Gaussian elimination with partial pivoting.
    for (int k = 0; k < 8; ++k) {
        int piv = k;
        double mx = fabs(A[k][k]);
        for (int r = k + 1; r < 8; ++r) {
            double a = fabs(A[r][k]);
            if (a > mx) { mx = a; piv = r; }
        }
        if (piv != k) {
            for (int c = k; c < 9; ++c) {
                double t = A[k][c]; A[k][c] = A[piv][c]; A[piv][c] = t;
            }
        }
        double inv = 1.0 / A[k][k];
        for (int r = k + 1; r < 8; ++r) {
            double f = A[r][k] * inv;
            for (int c = k; c < 9; ++c) A[r][c] -= f * A[k][c];
        }
    }
    // Back substitution.
    double h[8];
    for (int k = 7; k >= 0; --k) {
        double s = A[k][8];
        for (int c = k + 1; c < 8; ++c) s -= A[k][c] * h[c];
        h[k] = s / A[k][k];
    }

    float* Ho = Hout + b * 9;
    #pragma unroll
    for (int i = 0; i < 8; ++i) Ho[i] = (float)h[i];
    Ho[8] = 1.0f;
}

// ---------------------------------------------------------------------------
// Kernel 2: bilinear homography warp. One thread per (b, y, x) pixel,
// handles all 3 channels. Replicates reference f32 math exactly, including
// clipped-coordinate weights and the |T|<1e-7 -> +1e-6 guard.
// ---------------------------------------------------------------------------
__global__ __launch_bounds__(256) void warp_kernel(const float* __restrict__ src,
                                                   const float* __restrict__ Hbuf,
                                                   float* __restrict__ out) {
    int idx = blockIdx.x * 256 + threadIdx.x;
    if (idx >= BB * HW) return;
    int b = idx / HW;
    int p = idx - b * HW;
    int yi = p / WW;
    int xi = p - yi * WW;

    const float* Hm = Hbuf + b * 9;
    float gx = (float)xi, gy = (float)yi;
    float X = Hm[0] * gx + Hm[1] * gy + Hm[2];
    float Y = Hm[3] * gx + Hm[4] * gy + Hm[5];
    float T = Hm[6] * gx + Hm[7] * gy + Hm[8];
    if (!(fabsf(T) >= 1e-7f)) T += 1e-6f;
    float x = X / T;
    float y = Y / T;

    float fx = floorf(x), fy = floorf(y);
    float x0 = fminf(fmaxf(fx,        0.0f), (float)(WW - 1));
    float x1 = fminf(fmaxf(fx + 1.0f, 0.0f), (float)(WW - 1));
    float y0 = fminf(fmaxf(fy,        0.0f), (float)(HH - 1));
    float y1 = fminf(fmaxf(fy + 1.0f, 0.0f), (float)(HH - 1));

    float wa = (x1 - x) * (y1 - y);
    float wb = (x1 - x) * (y - y0);
    float wc = (x - x0) * (y1 - y);
    float wd = (x - x0) * (y - y0);

    int ix0 = (int)x0, ix1 = (int)x1, iy0 = (int)y0, iy1 = (int)y1;

    const float* sb = src + b * CC * HW;
    float* ob = out + b * CC * HW;
    int o00 = iy0 * WW + ix0;
    int o10 = iy1 * WW + ix0;
    int o01 = iy0 * WW + ix1;
    int o11 = iy1 * WW + ix1;

    #pragma unroll
    for (int c = 0; c < CC; ++c) {
        const float* sc = sb + c * HW;
        float Ia = sc[o00];
        float Ibv = sc[o10];
        float Ic = sc[o01];
        float Id = sc[o11];
        ob[c * HW + p] = wa * Ia + wb * Ibv + wc * Ic + wd * Id;
    }
}

extern "C" void kernel_launch(void* const* d_in, const int* in_sizes, int n_in,
                              void* d_out, int out_size, void* d_ws, size_t ws_size,
                              hipStream_t stream) {
    const float* src    = (const float*)d_in[0];
    const float* src_pt = (const float*)d_in[1];
    const float* dst_pt = (const float*)d_in[2];
    float* out = (float*)d_out;
    float* Hbuf = (float*)d_ws;  // 16 * 9 floats

    homography_kernel<<<1, 64, 0, stream>>>(src_pt, dst_pt, Hbuf);

    int total = BB * HW;
    int blocks = (total + 255) / 256;
    warp_kernel<<<blocks, 256, 0, stream>>>(src, Hbuf, out);
}